// Round 2
// baseline (1053.601 us; speedup 1.0000x reference)
//
#include <hip/hip_runtime.h>
#include <stdint.h>

#define T_STEPS 512
#define BATCH   4096
#define DIN     64
#define HID     70
#define KDIM    160      // K-span of one layer's weight panel (5 k-steps of 32)
#define KS      5
#define RB      16       // batch rows per block -> 256 blocks (1/CU)
#define WAVES   16       // 1024 threads (HW max). even wave -> L1, odd -> L0
#define NTHR    (WAVES*64)
#define NTILES  18       // tiles per layer; tile = 16 gate-rows = 4 h x 4 gates
#define ASP     232      // LDS panel row stride in shorts (464 B; dword stride 116 ≡ 20 mod 32
                         // -> b128 frag reads are aggregate-uniform 8/bank = conflict-free)
#define H1S     72       // h1f row stride (padded so tile-17 pad rows store harmlessly)

typedef __bf16 bf16x8 __attribute__((ext_vector_type(8)));
typedef float  f32x4  __attribute__((ext_vector_type(4)));
typedef unsigned short ushort_t;

#define NLOG2E   (-1.44269504088896340736f)
#define TWOLOG2E ( 2.88539008177792681472f)

__device__ __forceinline__ ushort_t f2bf(float f) {
    uint32_t u = __float_as_uint(f);
    u += 0x7fffu + ((u >> 16) & 1u);   // round-to-nearest-even
    return (ushort_t)(u >> 16);
}
__device__ __forceinline__ float sigm(float x) {
    return __builtin_amdgcn_rcpf(1.0f + __expf(-x));
}

// Fused LSTM pointwise on PRESCALED gates a = {-log2e*gi, -log2e*gf, 2log2e*gg, -log2e*go}
// 5 exp2 + 3 rcp. Pad chains (zero weights+bias) compute exactly h=0, c=0.
__device__ __forceinline__ float cell(const f32x4 a, float& cc) {
    float u0 = __builtin_amdgcn_exp2f(a[0]);
    float u1 = __builtin_amdgcn_exp2f(a[1]);
    float v  = __builtin_amdgcn_exp2f(fminf(a[2], 88.0f));
    float u3 = __builtin_amdgcn_exp2f(a[3]);
    float ig = (v - 1.0f) * __builtin_amdgcn_rcpf((1.0f + u0) * (1.0f + v));
    float f_ = __builtin_amdgcn_rcpf(1.0f + u1);
    float cn = fmaf(f_, cc, ig);
    cc = cn;
    float w  = __builtin_amdgcn_exp2f(fminf(cn * TWOLOG2E, 88.0f));
    return (w - 1.0f) * __builtin_amdgcn_rcpf((1.0f + u3) * (1.0f + w));
}

// Weight panels in MFMA operand-A layout, [NTILES][16 rows][KDIM] bf16, prescaled.
// Tile t, row m: h = 4t + (m>>2), gate = m&3 (torch gate-row = gate*70 + h); zero if h>=70.
__global__ void prep_kernel(const float* __restrict__ Wih0, const float* __restrict__ Whh0,
                            const float* __restrict__ bih0, const float* __restrict__ bhh0,
                            const float* __restrict__ Wih1, const float* __restrict__ Whh1,
                            const float* __restrict__ bih1, const float* __restrict__ bhh1,
                            ushort_t* __restrict__ W0p, ushort_t* __restrict__ W1p,
                            float* __restrict__ B0p, float* __restrict__ B1p) {
    int idx = blockIdx.x * 256 + threadIdx.x;
    const int n = NTILES * 16 * KDIM;   // 46080
    if (idx < n) {
        int row = idx / KDIM, k = idx - row * KDIM;
        int t = row >> 4, m = row & 15;
        int gate = m & 3, h = 4*t + (m >> 2);
        float sc = (gate == 2) ? TWOLOG2E : NLOG2E;
        float v0 = 0.f, v1 = 0.f;
        if (h < HID) {
            int g = gate * HID + h;
            if (k < 64)        v0 = Wih0[g*64 + k];
            else if (k < 134)  v0 = Whh0[g*HID + (k - 64)];
            if (k < 70)                   v1 = Wih1[g*HID + k];
            else if (k >= 80 && k < 150)  v1 = Whh1[g*HID + (k - 80)];
        }
        W0p[idx] = f2bf(sc * v0);
        W1p[idx] = f2bf(sc * v1);
    }
    if (idx < NTILES*16) {
        int t = idx >> 4, m = idx & 15;
        int gate = m & 3, h = 4*t + (m >> 2);
        float sc = (gate == 2) ? TWOLOG2E : NLOG2E;
        float s0 = 0.f, s1 = 0.f;
        if (h < HID) {
            int g = gate * HID + h;
            s0 = sc * (bih0[g] + bhh0[g]);
            s1 = sc * (bih1[g] + bhh1[g]);
        }
        B0p[idx] = s0; B1p[idx] = s1;
    }
}

__global__ __launch_bounds__(NTHR, 4) void lstm_kernel(
    const float* __restrict__ x,              // [T][B][64] fp32
    const ushort_t* __restrict__ W0p, const ushort_t* __restrict__ W1p,
    const float* __restrict__ B0p, const float* __restrict__ B1p,
    const float* __restrict__ W1h, const float* __restrict__ b1h,
    const float* __restrict__ W2h, const float* __restrict__ b2h,
    float* __restrict__ out)
{
    // Merged activation panel, double-buffered. Row = batch row (0..15).
    // cols 0..63: x(p+1) | 64..135: h0(p) | 144..215: h1(p-1) | pads stay 0.
    __shared__ alignas(16) ushort_t P[2][RB*ASP];
    __shared__ float h1f[RB*H1S];
    __shared__ float mid[RB*50];

    const int tid  = threadIdx.x;
    const int wave = tid >> 6;
    const int lane = tid & 63;
    const int n15  = lane & 15;          // batch row (MFMA B-frag col)
    const int q    = lane >> 4;          // k-chunk for frags; h-offset in C-tile
    const int blk  = blockIdx.x;
    const bool isL0 = (wave & 1);        // odd waves = layer0 -> per-SIMD layer-pure
    const int lw   = wave >> 1;          // 0..7 within layer
    const bool cw3 = (lw < 2);           // waves 0,1 of each layer carry 3 chains
    const int t0   = cw3 ? lw*3 : (6 + (lw-2)*2);
    const int hcol0 = t0*4 + q;

    const ushort_t* __restrict__ Wp = isL0 ? W0p : W1p;
    const float*    __restrict__ Bp = isL0 ? B0p : B1p;

    // Register weights (operand A). Lane (q,n15): row n15 of each tile, k=ks*32+q*8..+7.
    bf16x8 wA[3][KS];
    f32x4  bias[3];
    bias[2] = f32x4{0.f, 0.f, 0.f, 0.f};
    {
        const int r0 = (t0*16 + n15)*KDIM + q*8;
        const int r1 = ((t0+1)*16 + n15)*KDIM + q*8;
        #pragma unroll
        for (int ks = 0; ks < KS; ks++) {
            wA[0][ks] = *(const bf16x8*)(Wp + r0 + ks*32);
            wA[1][ks] = *(const bf16x8*)(Wp + r1 + ks*32);
        }
        bias[0] = *(const f32x4*)(Bp + t0*16 + q*4);
        bias[1] = *(const f32x4*)(Bp + (t0+1)*16 + q*4);
        if (cw3) {
            const int r2 = ((t0+2)*16 + n15)*KDIM + q*8;
            #pragma unroll
            for (int ks = 0; ks < KS; ks++)
                wA[2][ks] = *(const bf16x8*)(Wp + r2 + ks*32);
            bias[2] = *(const f32x4*)(Bp + (t0+2)*16 + q*4);
        }
    }
    const int kbase = (isL0 ? 0 : 64) + n15*ASP + q*8;   // B-frag base (shorts)
    const int hoff  = isL0 ? 64 : 144;

    float cc[3] = {0.f, 0.f, 0.f};

    // zero both panel buffers (h(-1)=0, pads stay zero forever)
    for (int i = tid; i < 2*RB*ASP; i += NTHR) (&P[0][0])[i] = 0;

    // x staging: waves 12..15 (cw=2, one per SIMD), one f32x4 per lane
    const bool xl   = (wave >= 12);
    const int  xt   = (wave - 12)*64 + lane;
    const int  xrow = (xt >> 4) & 15;
    const int  xcol = (xt & 15) * 4;
    const float* xptr = x + ((size_t)blk*RB + xrow)*DIN + xcol;

    f32x4 x0v, x1v, xcur;
    if (xl) {
        x0v  = *(const f32x4*)(xptr);
        x1v  = *(const f32x4*)(xptr + (size_t)1*(BATCH*DIN));
        xcur = *(const f32x4*)(xptr + (size_t)2*(BATCH*DIN));
    }
    __syncthreads();                 // zeros visible
    if (xl) {
        uint32_t a0, a1, b0, b1;
        asm("v_cvt_pk_bf16_f32 %0, %1, %2" : "=v"(a0) : "v"(x0v[0]), "v"(x0v[1]));
        asm("v_cvt_pk_bf16_f32 %0, %1, %2" : "=v"(a1) : "v"(x0v[2]), "v"(x0v[3]));
        asm("v_cvt_pk_bf16_f32 %0, %1, %2" : "=v"(b0) : "v"(x1v[0]), "v"(x1v[1]));
        asm("v_cvt_pk_bf16_f32 %0, %1, %2" : "=v"(b1) : "v"(x1v[2]), "v"(x1v[3]));
        uint2 pa; pa.x = a0; pa.y = a1;
        uint2 pb; pb.x = b0; pb.y = b1;
        *(uint2*)(&P[1][xrow*ASP + xcol]) = pa;   // x(0) -> prologue panel
        *(uint2*)(&P[0][xrow*ASP + xcol]) = pb;   // x(1) -> phase-0 panel
    }
    __syncthreads();

    // GEMM + cells for this wave's chains, reading B-frags from bp.
    auto gemm = [&](const ushort_t* bp, float* hv) __attribute__((always_inline)) {
        bf16x8 b[KS];
        #pragma unroll
        for (int ks = 0; ks < KS; ks++)
            b[ks] = *(const bf16x8*)(bp + ks*32);
        f32x4 a0 = bias[0], a1 = bias[1], a2 = bias[2];
        #pragma unroll
        for (int ks = 0; ks < KS; ks++) {
            a0 = __builtin_amdgcn_mfma_f32_16x16x32_bf16(wA[0][ks], b[ks], a0, 0,0,0);
            a1 = __builtin_amdgcn_mfma_f32_16x16x32_bf16(wA[1][ks], b[ks], a1, 0,0,0);
            if (cw3)
                a2 = __builtin_amdgcn_mfma_f32_16x16x32_bf16(wA[2][ks], b[ks], a2, 0,0,0);
        }
        hv[0] = cell(a0, cc[0]);
        hv[1] = cell(a1, cc[1]);
        if (cw3) hv[2] = cell(a2, cc[2]);
    };
    // h store into panel dst (bf16 via v_cvt_pk_bf16_f32, RNE)
    auto storeh = [&](ushort_t* hp, const float* hv) __attribute__((always_inline)) {
        uint32_t pk01;
        asm("v_cvt_pk_bf16_f32 %0, %1, %2" : "=v"(pk01) : "v"(hv[0]), "v"(hv[1]));
        hp[0] = (ushort_t)pk01;
        hp[4] = (ushort_t)(pk01 >> 16);
        if (cw3) {
            uint32_t pk2;
            asm("v_cvt_pk_bf16_f32 %0, %1, %2" : "=v"(pk2) : "v"(hv[2]), "v"(hv[2]));
            hp[8] = (ushort_t)pk2;
        }
    };

    // ---- prologue: L0 step 0 from P[1] = [x(0), h0(-1)=0] ----
    if (isL0) {
        float hv[3];
        gemm(&P[1][kbase], hv);
        storeh(&P[0][n15*ASP + 64 + hcol0], hv);   // h0(0)
    }
    __syncthreads();

    // ---- main loop: phase p computes L1 step p and L0 step p+1 ----
    // Relaxed barrier: lgkmcnt(0) only (no vmcnt drain) — x prefetch stays in flight.
    auto phase = [&](const int cur, const int p) __attribute__((always_inline)) {
        const int nxt = cur ^ 1;
        f32x4 xn;
        if (xl) {
            int tn = p + 3; if (tn > T_STEPS-1) tn = T_STEPS-1;
            xn = *(const f32x4*)(xptr + (size_t)tn*(BATCH*DIN));
        }
        float hv[3];
        gemm(&P[cur][kbase], hv);
        if (xl) {   // store x(p+2) (loaded last phase; long since arrived)
            uint32_t s0, s1;
            asm("v_cvt_pk_bf16_f32 %0, %1, %2" : "=v"(s0) : "v"(xcur[0]), "v"(xcur[1]));
            asm("v_cvt_pk_bf16_f32 %0, %1, %2" : "=v"(s1) : "v"(xcur[2]), "v"(xcur[3]));
            uint2 pv; pv.x = s0; pv.y = s1;
            *(uint2*)(&P[nxt][xrow*ASP + xcol]) = pv;
            xcur = xn;
        }
        storeh(&P[nxt][n15*ASP + hoff + hcol0], hv);
        asm volatile("s_waitcnt lgkmcnt(0)" ::: "memory");
        __builtin_amdgcn_s_barrier();
        asm volatile("" ::: "memory");
    };

    #pragma unroll 1
    for (int p = 0; p < T_STEPS - 2; p += 2) {
        phase(0, p);
        phase(1, p + 1);
    }
    phase(0, T_STEPS - 2);           // p = 510 -> produces h0(511), h1(510) in P[1]

    // ---- final phase p=511: L1 only, h1(511) straight to f32 LDS ----
    if (!isL0) {
        float hv[3];
        gemm(&P[1][kbase], hv);
        float* hd = &h1f[n15*H1S + hcol0];
        hd[0] = hv[0];
        hd[4] = hv[1];
        if (cw3) hd[8] = hv[2];
    }
    __syncthreads();

    // ---- head: out = sigmoid(W2 @ relu(W1 @ h1 + b1) + b2) ----
    for (int uu = tid; uu < RB*50; uu += NTHR) {
        const int r = uu / 50, j = uu - r*50;
        float s = b1h[j];
        const float* wgt = W1h + j*HID;
        const float* hh  = h1f + r*H1S;
        #pragma unroll 7
        for (int k = 0; k < HID; k++) s += wgt[k]*hh[k];
        mid[uu] = fmaxf(s, 0.0f);
    }
    __syncthreads();
    if (tid < RB) {
        float s = b2h[0];
        const float* m = mid + tid*50;
        #pragma unroll 10
        for (int j = 0; j < 50; j++) s += W2h[j]*m[j];
        out[blk*RB + tid] = sigm(s);
    }
}

extern "C" void kernel_launch(void* const* d_in, const int* in_sizes, int n_in,
                              void* d_out, int out_size, void* d_ws, size_t ws_size,
                              hipStream_t stream) {
    (void)in_sizes; (void)n_in; (void)out_size; (void)ws_size;
    const float* x    = (const float*)d_in[0];
    const float* Wih0 = (const float*)d_in[2];
    const float* Whh0 = (const float*)d_in[3];
    const float* bih0 = (const float*)d_in[4];
    const float* bhh0 = (const float*)d_in[5];
    const float* Wih1 = (const float*)d_in[6];
    const float* Whh1 = (const float*)d_in[7];
    const float* bih1 = (const float*)d_in[8];
    const float* bhh1 = (const float*)d_in[9];
    const float* W1h  = (const float*)d_in[10];
    const float* b1h  = (const float*)d_in[11];
    const float* W2h  = (const float*)d_in[12];
    const float* b2h  = (const float*)d_in[13];

    char* ws = (char*)d_ws;
    ushort_t* W0p = (ushort_t*)ws;                    // 18*16*160*2 = 92160 B
    ushort_t* W1p = (ushort_t*)(ws + 92160);          // 92160 B
    float*    B0p = (float*)(ws + 184320);            // 288 f32
    float*    B1p = (float*)(ws + 185472);            // 288 f32

    prep_kernel<<<180, 256, 0, stream>>>(Wih0, Whh0, bih0, bhh0,
                                         Wih1, Whh1, bih1, bhh1,
                                         W0p, W1p, B0p, B1p);
    lstm_kernel<<<BATCH/RB, NTHR, 0, stream>>>(x, W0p, W1p, B0p, B1p,
                                               W1h, b1h, W2h, b2h, (float*)d_out);
}

// Round 3
// 1032.098 us; speedup vs baseline: 1.0208x; 1.0208x over previous
//
#include <hip/hip_runtime.h>
#include <stdint.h>

#define T_STEPS 512
#define BATCH   4096
#define DIN     64
#define HID     70
#define KDIM    160      // K-span of one layer's weight panel (5 k-steps of 32)
#define KS      5
#define RB      16       // batch rows per block -> 256 blocks (1/CU)
#define WAVES   12       // 0..5 layer1, 6..11 layer0 (3 waves/SIMD) — 16 waves regressed (R2)
#define NTHR    (WAVES*64)
#define NTILES  18       // tiles per layer; tile = 16 gate-rows = 4 h x 4 gates
#define CH      3        // chains per wave: 6 waves x 3 = 18 tiles per layer
#define ASP     232      // LDS panel row stride in shorts (464 B; dword stride 116 ≡ 20 mod 32)
#define H1S     72       // h1f row stride (padded so tile-17 pad rows store harmlessly)

typedef __bf16 bf16x8 __attribute__((ext_vector_type(8)));
typedef float  f32x4  __attribute__((ext_vector_type(4)));
typedef unsigned short ushort_t;

#define NLOG2E   (-1.44269504088896340736f)
#define TWOLOG2E ( 2.88539008177792681472f)

__device__ __forceinline__ ushort_t f2bf(float f) {
    uint32_t u = __float_as_uint(f);
    u += 0x7fffu + ((u >> 16) & 1u);   // round-to-nearest-even
    return (ushort_t)(u >> 16);
}
__device__ __forceinline__ float sigm(float x) {
    return __builtin_amdgcn_rcpf(1.0f + __expf(-x));
}

// Fused LSTM pointwise on PRESCALED gates a = {-log2e*gi, -log2e*gf, 2log2e*gg, -log2e*go}
// 5 exp2 + 3 rcp. Pad chains (zero weights+bias) compute exactly h=0, c=0.
__device__ __forceinline__ float cell(const f32x4 a, float& cc) {
    float u0 = __builtin_amdgcn_exp2f(a[0]);
    float u1 = __builtin_amdgcn_exp2f(a[1]);
    float v  = __builtin_amdgcn_exp2f(fminf(a[2], 88.0f));
    float u3 = __builtin_amdgcn_exp2f(a[3]);
    float ig = (v - 1.0f) * __builtin_amdgcn_rcpf((1.0f + u0) * (1.0f + v));
    float f_ = __builtin_amdgcn_rcpf(1.0f + u1);
    float cn = fmaf(f_, cc, ig);
    cc = cn;
    float w  = __builtin_amdgcn_exp2f(fminf(cn * TWOLOG2E, 88.0f));
    return (w - 1.0f) * __builtin_amdgcn_rcpf((1.0f + u3) * (1.0f + w));
}

// h-region position permutation: value h = 4t + q sits at position offset q*18 + t
// (u -> h:  h = 4*(u%18) + u/18).  Makes the h-store banks 20*n15 + 9*q (+t/2):
// 32 distinct banks, 2 lanes each = conflict-free; chains at consecutive shorts.
//
// Weight panels in MFMA operand-A layout, [NTILES][16 rows][KDIM] bf16, prescaled.
// Tile t, row m: h_out = 4t + (m>>2), gate = m&3 (torch row = gate*70 + h); zero if h>=70.
// k cols, L0: k<64 -> Wih0[g][k]; 64<=k<136 -> Whh0[g][hval(k-64)]; else 0
//         L1: k<72 -> Wih1[g][hval(k)]; 80<=k<152 -> Whh1[g][hval(k-80)]; else 0
// Scale: gates i,f,o by -log2e; gate g by +2*log2e. Biases likewise (kept f32).
__global__ void prep_kernel(const float* __restrict__ Wih0, const float* __restrict__ Whh0,
                            const float* __restrict__ bih0, const float* __restrict__ bhh0,
                            const float* __restrict__ Wih1, const float* __restrict__ Whh1,
                            const float* __restrict__ bih1, const float* __restrict__ bhh1,
                            ushort_t* __restrict__ W0p, ushort_t* __restrict__ W1p,
                            float* __restrict__ B0p, float* __restrict__ B1p) {
    int idx = blockIdx.x * 256 + threadIdx.x;
    const int n = NTILES * 16 * KDIM;   // 46080
    if (idx < n) {
        int row = idx / KDIM, k = idx - row * KDIM;
        int t = row >> 4, m = row & 15;
        int gate = m & 3, h = 4*t + (m >> 2);
        float sc = (gate == 2) ? TWOLOG2E : NLOG2E;
        float v0 = 0.f, v1 = 0.f;
        if (h < HID) {
            int g = gate * HID + h;
            // layer 0
            if (k < 64) {
                v0 = Wih0[g*64 + k];
            } else if (k < 136) {
                int u = k - 64, hh = 4*(u % 18) + u/18;
                if (hh < HID) v0 = Whh0[g*HID + hh];
            }
            // layer 1 (panel col = 64 + k)
            if (k < 72) {
                int hh = 4*(k % 18) + k/18;
                if (hh < HID) v1 = Wih1[g*HID + hh];
            } else if (k >= 80 && k < 152) {
                int u = k - 80, hh = 4*(u % 18) + u/18;
                if (hh < HID) v1 = Whh1[g*HID + hh];
            }
        }
        W0p[idx] = f2bf(sc * v0);
        W1p[idx] = f2bf(sc * v1);
    }
    if (idx < NTILES*16) {
        int t = idx >> 4, m = idx & 15;
        int gate = m & 3, h = 4*t + (m >> 2);
        float sc = (gate == 2) ? TWOLOG2E : NLOG2E;
        float s0 = 0.f, s1 = 0.f;
        if (h < HID) {
            int g = gate * HID + h;
            s0 = sc * (bih0[g] + bhh0[g]);
            s1 = sc * (bih1[g] + bhh1[g]);
        }
        B0p[idx] = s0; B1p[idx] = s1;
    }
}

__global__ __launch_bounds__(NTHR) void lstm_kernel(
    const float* __restrict__ x,              // [T][B][64] fp32
    const ushort_t* __restrict__ W0p, const ushort_t* __restrict__ W1p,
    const float* __restrict__ B0p, const float* __restrict__ B1p,
    const float* __restrict__ W1h, const float* __restrict__ b1h,
    const float* __restrict__ W2h, const float* __restrict__ b2h,
    float* __restrict__ out)
{
    // Merged activation panel, double-buffered. Row = batch row (0..15).
    // cols 0..63: x(p+1) | 64..135: h0(p) permuted | 144..215: h1(p-1) permuted | pads 0.
    __shared__ alignas(16) ushort_t P[2][RB*ASP];
    __shared__ float h1f[RB*H1S];
    __shared__ float mid[RB*50];

    const int tid  = threadIdx.x;
    const int wave = tid >> 6;
    const int lane = tid & 63;
    const int n15  = lane & 15;          // batch row (MFMA B-frag col)
    const int q    = lane >> 4;          // k-chunk for frags; h-offset in C-tile
    const int blk  = blockIdx.x;
    const bool isL0 = (wave >= 6);
    const int lw   = isL0 ? wave - 6 : wave;   // 0..5 within layer
    const int t0   = lw * CH;

    const ushort_t* __restrict__ Wp = isL0 ? W0p : W1p;
    const float*    __restrict__ Bp = isL0 ? B0p : B1p;

    // Register weights (operand A). Lane (q,n15): row n15 of each tile, k=ks*32+q*8..+7.
    bf16x8 wA[CH][KS];
    f32x4  bias[CH];
    #pragma unroll
    for (int c = 0; c < CH; c++) {
        const int rowb = ((t0 + c)*16 + n15)*KDIM + q*8;
        #pragma unroll
        for (int ks = 0; ks < KS; ks++)
            wA[c][ks] = *(const bf16x8*)(Wp + rowb + ks*32);
        bias[c] = *(const f32x4*)(Bp + (t0 + c)*16 + q*4);
    }
    const int kbase = (isL0 ? 0 : 64) + n15*ASP + q*8;           // B-frag base (shorts)
    const int hpos  = n15*ASP + (isL0 ? 64 : 144) + q*18 + t0;   // c0 store position
    const bool evenT = ((t0 & 1) == 0);

    float cc[CH] = {0.f, 0.f, 0.f};

    // zero both panel buffers (h(-1)=0, pads stay zero forever)
    for (int i = tid; i < 2*RB*ASP; i += NTHR) (&P[0][0])[i] = 0;

    // x staging: threads 384..639 (L0 waves 6..9), one f32x4 each
    const int  xt   = tid - 384;
    const bool xl   = (xt >= 0) && (xt < 256);
    const int  xrow = xt >> 4;
    const int  xcol = (xt & 15) * 4;
    const float* xptr = x + ((size_t)blk*RB + xrow)*DIN + xcol;

    f32x4 x0v, x1v, xcur;
    if (xl) {
        x0v  = *(const f32x4*)(xptr);
        x1v  = *(const f32x4*)(xptr + (size_t)1*(BATCH*DIN));
        xcur = *(const f32x4*)(xptr + (size_t)2*(BATCH*DIN));
    }
    __syncthreads();                 // zeros visible
    if (xl) {
        uint32_t a0, a1, b0, b1;
        asm("v_cvt_pk_bf16_f32 %0, %1, %2" : "=v"(a0) : "v"(x0v[0]), "v"(x0v[1]));
        asm("v_cvt_pk_bf16_f32 %0, %1, %2" : "=v"(a1) : "v"(x0v[2]), "v"(x0v[3]));
        asm("v_cvt_pk_bf16_f32 %0, %1, %2" : "=v"(b0) : "v"(x1v[0]), "v"(x1v[1]));
        asm("v_cvt_pk_bf16_f32 %0, %1, %2" : "=v"(b1) : "v"(x1v[2]), "v"(x1v[3]));
        uint2 pa; pa.x = a0; pa.y = a1;
        uint2 pb; pb.x = b0; pb.y = b1;
        *(uint2*)(&P[1][xrow*ASP + xcol]) = pa;   // x(0) -> prologue panel
        *(uint2*)(&P[0][xrow*ASP + xcol]) = pb;   // x(1) -> phase-0 panel
    }
    __syncthreads();

    // GEMM + cells for this wave's 3 chains, reading B-frags from bp.
    auto gemm = [&](const ushort_t* bp, float* hv) __attribute__((always_inline)) {
        bf16x8 b[KS];
        #pragma unroll
        for (int ks = 0; ks < KS; ks++)
            b[ks] = *(const bf16x8*)(bp + ks*32);
        f32x4 a0 = bias[0], a1 = bias[1], a2 = bias[2];
        #pragma unroll
        for (int ks = 0; ks < KS; ks++) {
            a0 = __builtin_amdgcn_mfma_f32_16x16x32_bf16(wA[0][ks], b[ks], a0, 0,0,0);
            a1 = __builtin_amdgcn_mfma_f32_16x16x32_bf16(wA[1][ks], b[ks], a1, 0,0,0);
            a2 = __builtin_amdgcn_mfma_f32_16x16x32_bf16(wA[2][ks], b[ks], a2, 0,0,0);
        }
        hv[0] = cell(a0, cc[0]);
        hv[1] = cell(a1, cc[1]);
        hv[2] = cell(a2, cc[2]);
    };
    // h store: chains sit at consecutive shorts hpos..hpos+2 -> one b32 + one b16,
    // picked by t0 parity to keep the b32 dword-aligned. Banks 2-way (free).
    auto storeh = [&](ushort_t* Pn, const float* hv) __attribute__((always_inline)) {
        uint32_t pkA, pkB;
        if (evenT) {
            asm("v_cvt_pk_bf16_f32 %0, %1, %2" : "=v"(pkA) : "v"(hv[0]), "v"(hv[1]));
            asm("v_cvt_pk_bf16_f32 %0, %1, %2" : "=v"(pkB) : "v"(hv[2]), "v"(hv[2]));
            *(uint32_t*)(Pn + hpos) = pkA;
            Pn[hpos + 2] = (ushort_t)pkB;
        } else {
            asm("v_cvt_pk_bf16_f32 %0, %1, %2" : "=v"(pkA) : "v"(hv[0]), "v"(hv[0]));
            asm("v_cvt_pk_bf16_f32 %0, %1, %2" : "=v"(pkB) : "v"(hv[1]), "v"(hv[2]));
            Pn[hpos] = (ushort_t)pkA;
            *(uint32_t*)(Pn + hpos + 1) = pkB;
        }
    };

    // ---- prologue: L0 step 0 from P[1] = [x(0), h0(-1)=0] ----
    if (isL0) {
        float hv[CH];
        gemm(&P[1][kbase], hv);
        storeh(&P[0][0], hv);          // h0(0)
    }
    __syncthreads();

    // ---- main loop: phase p computes L1 step p and L0 step p+1 ----
    auto phase = [&](const int cur, const int p) __attribute__((always_inline)) {
        const int nxt = cur ^ 1;
        f32x4 xn;
        if (xl) {
            int tn = p + 3; if (tn > T_STEPS-1) tn = T_STEPS-1;
            xn = *(const f32x4*)(xptr + (size_t)tn*(BATCH*DIN));
        }
        float hv[CH];
        gemm(&P[cur][kbase], hv);
        if (xl) {   // store x(p+2) (loaded last phase; long since arrived)
            uint32_t s0, s1;
            asm("v_cvt_pk_bf16_f32 %0, %1, %2" : "=v"(s0) : "v"(xcur[0]), "v"(xcur[1]));
            asm("v_cvt_pk_bf16_f32 %0, %1, %2" : "=v"(s1) : "v"(xcur[2]), "v"(xcur[3]));
            uint2 pv; pv.x = s0; pv.y = s1;
            *(uint2*)(&P[nxt][xrow*ASP + xcol]) = pv;
            xcur = xn;
        }
        storeh(&P[nxt][0], hv);
        __syncthreads();
    };

    #pragma unroll 1
    for (int p = 0; p < T_STEPS - 2; p += 2) {
        phase(0, p);
        phase(1, p + 1);
    }
    phase(0, T_STEPS - 2);           // p = 510 -> h0(511), h1(510) land in P[1]

    // ---- final phase p=511: L1 only, h1(511) straight to f32 LDS (real h order) ----
    if (!isL0) {
        float hv[CH];
        gemm(&P[1][kbase], hv);
        float* hd = &h1f[n15*H1S + t0*4 + q];
        hd[0] = hv[0];
        hd[4] = hv[1];
        hd[8] = hv[2];
    }
    __syncthreads();

    // ---- head: out = sigmoid(W2 @ relu(W1 @ h1 + b1) + b2) ----
    for (int uu = tid; uu < RB*50; uu += NTHR) {
        const int r = uu / 50, j = uu - r*50;
        float s = b1h[j];
        const float* wgt = W1h + j*HID;
        const float* hh  = h1f + r*H1S;
        #pragma unroll 7
        for (int k = 0; k < HID; k++) s += wgt[k]*hh[k];
        mid[uu] = fmaxf(s, 0.0f);
    }
    __syncthreads();
    if (tid < RB) {
        float s = b2h[0];
        const float* m = mid + tid*50;
        #pragma unroll 10
        for (int j = 0; j < 50; j++) s += W2h[j]*m[j];
        out[blk*RB + tid] = sigm(s);
    }
}

extern "C" void kernel_launch(void* const* d_in, const int* in_sizes, int n_in,
                              void* d_out, int out_size, void* d_ws, size_t ws_size,
                              hipStream_t stream) {
    (void)in_sizes; (void)n_in; (void)out_size; (void)ws_size;
    const float* x    = (const float*)d_in[0];
    const float* Wih0 = (const float*)d_in[2];
    const float* Whh0 = (const float*)d_in[3];
    const float* bih0 = (const float*)d_in[4];
    const float* bhh0 = (const float*)d_in[5];
    const float* Wih1 = (const float*)d_in[6];
    const float* Whh1 = (const float*)d_in[7];
    const float* bih1 = (const float*)d_in[8];
    const float* bhh1 = (const float*)d_in[9];
    const float* W1h  = (const float*)d_in[10];
    const float* b1h  = (const float*)d_in[11];
    const float* W2h  = (const float*)d_in[12];
    const float* b2h  = (const float*)d_in[13];

    char* ws = (char*)d_ws;
    ushort_t* W0p = (ushort_t*)ws;                    // 18*16*160*2 = 92160 B
    ushort_t* W1p = (ushort_t*)(ws + 92160);          // 92160 B
    float*    B0p = (float*)(ws + 184320);            // 288 f32
    float*    B1p = (float*)(ws + 185472);            // 288 f32

    prep_kernel<<<180, 256, 0, stream>>>(Wih0, Whh0, bih0, bhh0,
                                         Wih1, Whh1, bih1, bhh1,
                                         W0p, W1p, B0p, B1p);
    lstm_kernel<<<BATCH/RB, NTHR, 0, stream>>>(x, W0p, W1p, B0p, B1p,
                                               W1h, b1h, W2h, b2h, (float*)d_out);
}